// Round 5
// baseline (319.060 us; speedup 1.0000x reference)
//
#include <hip/hip_runtime.h>
#include <math.h>

#define B_    2
#define N_    2048
#define DIM_  1024
#define H_    16
#define D_    64
#define INNER_ 1024
#define QKVC_ 3072

typedef __attribute__((ext_vector_type(8))) short short8;
typedef __attribute__((ext_vector_type(4))) short short4v;
typedef __attribute__((ext_vector_type(4))) float f32x4;
typedef __attribute__((ext_vector_type(4))) float float4v;

static __device__ __forceinline__ unsigned short f2bf(float f) {
    unsigned int u = __float_as_uint(f);
    u = (u + 0x7fff + ((u >> 16) & 1)) >> 16;   // RNE
    return (unsigned short)u;
}
static __device__ __forceinline__ float bf2f(unsigned short b) {
    return __uint_as_float(((unsigned int)b) << 16);
}

static __device__ __forceinline__ void gload16(const void* g, void* l) {
    __builtin_amdgcn_global_load_lds((__attribute__((address_space(1))) void*)(g),
                                     (__attribute__((address_space(3))) void*)(l),
                                     16, 0, 0);
}

// ---------------------------------------------------------------------------
// convert_x: fp32 (rows x 1024) -> bf16 hi/lo, same layout. 8 elems/thread.
// ---------------------------------------------------------------------------
__global__ __launch_bounds__(256) void convert_x(const float* __restrict__ X,
                                                 unsigned short* __restrict__ Xhi,
                                                 unsigned short* __restrict__ Xlo) {
    int t = blockIdx.x * blockDim.x + threadIdx.x;
    size_t off = (size_t)t * 8;
    float4v a = *(const float4v*)(X + off);
    float4v b = *(const float4v*)(X + off + 4);
    short8 hi, lo;
#pragma unroll
    for (int j = 0; j < 4; ++j) {
        unsigned short h = f2bf(a[j]); hi[j] = (short)h; lo[j] = (short)f2bf(a[j] - bf2f(h));
        unsigned short h2 = f2bf(b[j]); hi[4 + j] = (short)h2; lo[4 + j] = (short)f2bf(b[j] - bf2f(h2));
    }
    *(short8*)(Xhi + off) = hi;
    *(short8*)(Xlo + off) = lo;
}

// ---------------------------------------------------------------------------
// convert_w_T: W fp32 (K=1024 x Nw) -> W^T bf16 hi/lo (Nw x 1024).
// ---------------------------------------------------------------------------
__global__ __launch_bounds__(256) void convert_w_T(const float* __restrict__ W,
                                                   unsigned short* __restrict__ Thi,
                                                   unsigned short* __restrict__ Tlo,
                                                   int Nw) {
    __shared__ unsigned short Shi[64][65];
    __shared__ unsigned short Slo[64][65];
    const int tid = threadIdx.x;
    const int n0 = blockIdx.x * 64;
    const int k0 = blockIdx.y * 64;
#pragma unroll
    for (int l = 0; l < 16; ++l) {
        int idx = tid + l * 256;
        int r = idx >> 6, c = idx & 63;
        float v = W[(size_t)(k0 + r) * Nw + n0 + c];
        unsigned short h = f2bf(v);
        Shi[c][r] = h;
        Slo[c][r] = f2bf(v - bf2f(h));
    }
    __syncthreads();
#pragma unroll
    for (int l = 0; l < 16; ++l) {
        int idx = tid + l * 256;
        int r = idx >> 6, c = idx & 63;
        size_t o = (size_t)(n0 + r) * 1024 + k0 + c;
        Thi[o] = Shi[r][c];
        Tlo[o] = Slo[r][c];
    }
}

// ---------------------------------------------------------------------------
// Split-bf16 GEMM core: C(M x N) = A(M x 1024) * B^T(N x 1024), fp32 acc.
// ---------------------------------------------------------------------------
#define GEMM_STAGE(gA_hi, gA_lo, gB_hi, gB_lo)                                     \
    {                                                                              \
        int c0 = w * 2, c1 = w * 2 + 1;                                            \
        int ra0 = c0 * 16 + (lane >> 2), ra1 = c1 * 16 + (lane >> 2);              \
        int kc = (lane & 3) * 8;                                                   \
        gload16(gA_hi + (size_t)(m0 + ra0) * 1024 + k0 + kc, sAhi + c0 * 512);     \
        gload16(gA_hi + (size_t)(m0 + ra1) * 1024 + k0 + kc, sAhi + c1 * 512);     \
        gload16(gA_lo + (size_t)(m0 + ra0) * 1024 + k0 + kc, sAlo + c0 * 512);     \
        gload16(gA_lo + (size_t)(m0 + ra1) * 1024 + k0 + kc, sAlo + c1 * 512);     \
        gload16(gB_hi + (size_t)(n0 + ra0) * 1024 + k0 + kc, sBhi + c0 * 512);     \
        gload16(gB_hi + (size_t)(n0 + ra1) * 1024 + k0 + kc, sBhi + c1 * 512);     \
        gload16(gB_lo + (size_t)(n0 + ra0) * 1024 + k0 + kc, sBlo + c0 * 512);     \
        gload16(gB_lo + (size_t)(n0 + ra1) * 1024 + k0 + kc, sBlo + c1 * 512);     \
    }

#define GEMM_BODY()                                                                \
    short8 ah[4], al[4], bh[4], bl[4];                                             \
    _Pragma("unroll") for (int f = 0; f < 4; ++f) {                                \
        int offa = (wr + f * 16 + (lane & 15)) * 32 + (lane >> 4) * 8;             \
        ah[f] = *(const short8*)&sAhi[offa];                                       \
        al[f] = *(const short8*)&sAlo[offa];                                       \
        int offb = (wc + f * 16 + (lane & 15)) * 32 + (lane >> 4) * 8;             \
        bh[f] = *(const short8*)&sBhi[offb];                                       \
        bl[f] = *(const short8*)&sBlo[offb];                                       \
    }                                                                              \
    _Pragma("unroll") for (int i = 0; i < 4; ++i)                                  \
        _Pragma("unroll") for (int j = 0; j < 4; ++j) {                            \
            acc[i][j] = __builtin_amdgcn_mfma_f32_16x16x32_bf16(ah[i], bh[j], acc[i][j], 0, 0, 0); \
            acc[i][j] = __builtin_amdgcn_mfma_f32_16x16x32_bf16(al[i], bh[j], acc[i][j], 0, 0, 0); \
            acc[i][j] = __builtin_amdgcn_mfma_f32_16x16x32_bf16(ah[i], bl[j], acc[i][j], 0, 0, 0); \
        }

__global__ __launch_bounds__(256) void qkv_gemm_mfma(const unsigned short* __restrict__ Ahi,
                                                     const unsigned short* __restrict__ Alo,
                                                     const unsigned short* __restrict__ Bhi,
                                                     const unsigned short* __restrict__ Blo,
                                                     unsigned short* __restrict__ Qb,
                                                     unsigned short* __restrict__ Kb,
                                                     unsigned short* __restrict__ Vb) {
    __shared__ __align__(16) unsigned short sAhi[4096], sAlo[4096], sBhi[4096], sBlo[4096];
    const int tid = threadIdx.x;
    const int lane = tid & 63, w = tid >> 6;
    const int wr = (w >> 1) * 64, wc = (w & 1) * 64;
    const int m0 = blockIdx.y * 128, n0 = blockIdx.x * 128;
    f32x4 acc[4][4] = {};

    for (int k0 = 0; k0 < 1024; k0 += 32) {
        GEMM_STAGE(Ahi, Alo, Bhi, Blo);
        __syncthreads();
        GEMM_BODY();
        __syncthreads();
    }

#pragma unroll
    for (int i = 0; i < 4; ++i) {
        int mbase = m0 + wr + i * 16 + (lane >> 4) * 4;
#pragma unroll
        for (int j = 0; j < 4; ++j) {
            int col = n0 + wc + j * 16 + (lane & 15);
            int seg = col >> 10;
            int wcol = col & 1023;
            int h = wcol >> 6, dd = wcol & 63;
            unsigned short* dst = (seg == 0) ? Qb : (seg == 1 ? Kb : Vb);
#pragma unroll
            for (int r = 0; r < 4; ++r) {
                int row = mbase + r;
                int b = row >> 11, n = row & (N_ - 1);
                dst[((size_t)(b * H_ + h) * N_ + n) * D_ + dd] = f2bf(acc[i][j][r]);
            }
        }
    }
}

__global__ __launch_bounds__(256) void out_gemm_mfma(const unsigned short* __restrict__ Ahi,
                                                     const unsigned short* __restrict__ Alo,
                                                     const unsigned short* __restrict__ Bhi,
                                                     const unsigned short* __restrict__ Blo,
                                                     const float* __restrict__ bias,
                                                     float* __restrict__ C) {
    __shared__ __align__(16) unsigned short sAhi[4096], sAlo[4096], sBhi[4096], sBlo[4096];
    const int tid = threadIdx.x;
    const int lane = tid & 63, w = tid >> 6;
    const int wr = (w >> 1) * 64, wc = (w & 1) * 64;
    const int m0 = blockIdx.y * 128, n0 = blockIdx.x * 128;
    f32x4 acc[4][4] = {};

    for (int k0 = 0; k0 < 1024; k0 += 32) {
        GEMM_STAGE(Ahi, Alo, Bhi, Blo);
        __syncthreads();
        GEMM_BODY();
        __syncthreads();
    }

#pragma unroll
    for (int i = 0; i < 4; ++i) {
        int mbase = m0 + wr + i * 16 + (lane >> 4) * 4;
#pragma unroll
        for (int j = 0; j < 4; ++j) {
            int col = n0 + wc + j * 16 + (lane & 15);
            float bv = bias[col];
#pragma unroll
            for (int r = 0; r < 4; ++r)
                C[(size_t)(mbase + r) * DIM_ + col] = acc[i][j][r] + bv;
        }
    }
}

// ---------------------------------------------------------------------------
// RoPE in-place on bf16 Q and K. Q additionally pre-scaled by
// 0.125*log2(e) so attention softmax runs in exp2 domain with no per-elem
// scale (0.125 = 1/sqrt(64); log2e folds exp->exp2).
// ---------------------------------------------------------------------------
#define QSCALE 0.180336879963f   // 0.125 * log2(e)
__global__ void rope_kernel(unsigned short* __restrict__ Qb,
                            unsigned short* __restrict__ Kb) {
    const int total = B_ * H_ * N_ * (D_ / 2);
    for (int p = blockIdx.x * blockDim.x + threadIdx.x; p < total;
         p += gridDim.x * blockDim.x) {
        int d2 = p & 31;
        int rest = p >> 5;
        int n = rest & (N_ - 1);
        size_t off = (size_t)rest * D_ + 2 * d2;
        float freq = powf(10000.0f, -(float)d2 * (1.0f / 32.0f));
        float ang = (float)n * freq;
        float s, c;
        sincosf(ang, &s, &c);

        unsigned int uq = *(unsigned int*)(Qb + off);
        float q0 = __uint_as_float(uq << 16);
        float q1 = __uint_as_float(uq & 0xffff0000u);
        *(unsigned int*)(Qb + off) =
            (unsigned int)f2bf((q0 * c - q1 * s) * QSCALE) |
            ((unsigned int)f2bf((q1 * c + q0 * s) * QSCALE) << 16);

        unsigned int uk = *(unsigned int*)(Kb + off);
        float k0 = __uint_as_float(uk << 16);
        float k1 = __uint_as_float(uk & 0xffff0000u);
        *(unsigned int*)(Kb + off) = (unsigned int)f2bf(k0 * c - k1 * s) |
                                     ((unsigned int)f2bf(k1 * c + k0 * s) << 16);
    }
}

// ---------------------------------------------------------------------------
// Flash attention v3: rotated software pipeline.
// Per iteration: barrier -> issue K(ti)+V(ti+1) global loads -> PV(ti-1)
// (covers K latency) -> QK(ti) -> softmax(ti, exp2 domain) -> commit V(ti+1).
// V lives in a 3-buffer LDS ring; P stays in registers (swapped-QK layout).
// ---------------------------------------------------------------------------
#define PADV 68
#define NT   (N_ / 64)
__global__ __launch_bounds__(512, 4) void attn_mfma(const unsigned short* __restrict__ Qb,
                                                    const unsigned short* __restrict__ Kb,
                                                    const unsigned short* __restrict__ Vb,
                                                    unsigned short* __restrict__ Ohi,
                                                    unsigned short* __restrict__ Olo) {
    __shared__ __align__(16) unsigned short Vt[3][64][PADV];   // V^T ring: [d][kv]
    const int tid = threadIdx.x;
    const int w = tid >> 6;
    const int l = tid & 63;
    const int lr = l & 15, lg = l >> 4;
    const int bh = blockIdx.y;
    const int q0 = blockIdx.x * 128;
    const size_t base = (size_t)bh * N_ * D_;

    const unsigned short* qrow = Qb + base + (size_t)(q0 + w * 16 + lr) * D_ + lg * 8;
    const short8 qf0 = *(const short8*)qrow;
    const short8 qf1 = *(const short8*)(qrow + 32);

    const int sd0 = (tid & 15) * 4;
    const int skv = (tid >> 4) * 2;

    f32x4 oacc[4] = {};                 // [dt]: q=lg*4+r, d=dt*16+lr
    float mrow = -1e30f, lsum = 0.f;    // per-lane state for q-row lr
    short8 pa_prev[2] = {};             // carried P A-frags (tile ti-1)
    float al_prev = 0.f;

    // prologue: stage V tile 0 -> ring slot 0
    {
        short4v r0 = *(const short4v*)(Vb + base + (size_t)(skv + 0) * D_ + sd0);
        short4v r1 = *(const short4v*)(Vb + base + (size_t)(skv + 1) * D_ + sd0);
#pragma unroll
        for (int j = 0; j < 4; ++j) {
            unsigned int pk = (unsigned int)(unsigned short)r0[j] |
                              ((unsigned int)(unsigned short)r1[j] << 16);
            *(unsigned int*)&Vt[0][sd0 + j][skv] = pk;
        }
    }

    int rd = 2, cu = 0, wr_ = 1;        // ring slots: (ti-1)%3, ti%3, (ti+1)%3

    for (int ti = 0; ti < NT; ++ti) {
        __syncthreads();

        // ---- issue K(ti) loads ----
        short8 kf[8];
        const unsigned short* kbase = Kb + base + (size_t)(ti * 64) * D_;
#pragma unroll
        for (int t = 0; t < 4; ++t) {
            const unsigned short* krow = kbase + (size_t)(t * 16 + lr) * D_ + lg * 8;
            kf[2 * t]     = *(const short8*)krow;
            kf[2 * t + 1] = *(const short8*)(krow + 32);
        }
        // ---- issue V(ti+1) loads ----
        short4v n0v = {}, n1v = {};
        if (ti + 1 < NT) {
            const unsigned short* nsrc = Vb + base + (size_t)((ti + 1) * 64 + skv) * D_ + sd0;
            n0v = *(const short4v*)nsrc;
            n1v = *(const short4v*)(nsrc + D_);
        }

        // ---- PV(ti-1): covers K load latency ----
        if (ti > 0) {
#pragma unroll
            for (int r = 0; r < 4; ++r) {
                float alq = __shfl(al_prev, lg * 4 + r);
#pragma unroll
                for (int dt = 0; dt < 4; ++dt) oacc[dt][r] *= alq;
            }
            __builtin_amdgcn_s_setprio(1);
#pragma unroll
            for (int m2 = 0; m2 < 2; ++m2)
#pragma unroll
                for (int dt = 0; dt < 4; ++dt) {
                    short4v v0 = *(const short4v*)&Vt[rd][dt * 16 + lr][m2 * 32 + lg * 4];
                    short4v v1 = *(const short4v*)&Vt[rd][dt * 16 + lr][m2 * 32 + 16 + lg * 4];
                    short8 vb = {v0[0], v0[1], v0[2], v0[3], v1[0], v1[1], v1[2], v1[3]};
                    oacc[dt] = __builtin_amdgcn_mfma_f32_16x16x32_bf16(pa_prev[m2], vb, oacc[dt], 0, 0, 0);
                }
            __builtin_amdgcn_s_setprio(0);
        }

        // ---- QK(ti): S^T = K.Q^T (values already in log2 domain) ----
        f32x4 sacc[4] = {};
        __builtin_amdgcn_s_setprio(1);
#pragma unroll
        for (int t = 0; t < 4; ++t) {
            sacc[t] = __builtin_amdgcn_mfma_f32_16x16x32_bf16(kf[2 * t], qf0, sacc[t], 0, 0, 0);
            sacc[t] = __builtin_amdgcn_mfma_f32_16x16x32_bf16(kf[2 * t + 1], qf1, sacc[t], 0, 0, 0);
        }
        __builtin_amdgcn_s_setprio(0);

        // ---- softmax (exp2 domain) ----
        float tm = -1e30f;
#pragma unroll
        for (int t = 0; t < 4; ++t)
#pragma unroll
            for (int r = 0; r < 4; ++r) tm = fmaxf(tm, sacc[t][r]);
        tm = fmaxf(tm, __shfl_xor(tm, 16));
        tm = fmaxf(tm, __shfl_xor(tm, 32));
        float nm = fmaxf(mrow, tm);
        float al = __builtin_amdgcn_exp2f(mrow - nm);
        mrow = nm;

        short8 pan[2];
        float ps = 0.f;
#pragma unroll
        for (int t = 0; t < 4; ++t)
#pragma unroll
            for (int r = 0; r < 4; ++r) {
                float e = __builtin_amdgcn_exp2f(sacc[t][r] - nm);
                ps += e;
                pan[t >> 1][(t & 1) * 4 + r] = (short)f2bf(e);
            }
        ps += __shfl_xor(ps, 16);
        ps += __shfl_xor(ps, 32);
        lsum = lsum * al + ps;
        pa_prev[0] = pan[0];
        pa_prev[1] = pan[1];
        al_prev = al;

        // ---- commit V(ti+1) into ring slot wr_ ----
        if (ti + 1 < NT) {
#pragma unroll
            for (int j = 0; j < 4; ++j) {
                unsigned int pk = (unsigned int)(unsigned short)n0v[j] |
                                  ((unsigned int)(unsigned short)n1v[j] << 16);
                *(unsigned int*)&Vt[wr_][sd0 + j][skv] = pk;
            }
        }
        int t_ = rd; rd = cu; cu = wr_; wr_ = t_;
    }

    // ---- epilogue PV(NT-1) ----
    {
#pragma unroll
        for (int r = 0; r < 4; ++r) {
            float alq = __shfl(al_prev, lg * 4 + r);
#pragma unroll
            for (int dt = 0; dt < 4; ++dt) oacc[dt][r] *= alq;
        }
#pragma unroll
        for (int m2 = 0; m2 < 2; ++m2)
#pragma unroll
            for (int dt = 0; dt < 4; ++dt) {
                short4v v0 = *(const short4v*)&Vt[rd][dt * 16 + lr][m2 * 32 + lg * 4];
                short4v v1 = *(const short4v*)&Vt[rd][dt * 16 + lr][m2 * 32 + 16 + lg * 4];
                short8 vb = {v0[0], v0[1], v0[2], v0[3], v1[0], v1[1], v1[2], v1[3]};
                oacc[dt] = __builtin_amdgcn_mfma_f32_16x16x32_bf16(pa_prev[m2], vb, oacc[dt], 0, 0, 0);
            }
    }

    // ---- final write ----
    int b = bh >> 4, h = bh & 15;
#pragma unroll
    for (int r = 0; r < 4; ++r) {
        float ls = __shfl(lsum, lg * 4 + r);
        float inv = 1.0f / ls;
        size_t orow = ((size_t)b * N_ + q0 + w * 16 + lg * 4 + r) * INNER_ + h * 64 + lr;
#pragma unroll
        for (int dt = 0; dt < 4; ++dt) {
            float o = oacc[dt][r] * inv;
            unsigned short hi = f2bf(o);
            Ohi[orow + 16 * dt] = hi;
            Olo[orow + 16 * dt] = f2bf(o - bf2f(hi));
        }
    }
}

// ---------------------------------------------------------------------------
extern "C" void kernel_launch(void* const* d_in, const int* in_sizes, int n_in,
                              void* d_out, int out_size, void* d_ws, size_t ws_size,
                              hipStream_t stream) {
    const float* x     = (const float*)d_in[0];
    const float* w_qkv = (const float*)d_in[1];
    const float* w_out = (const float*)d_in[2];
    const float* b_out = (const float*)d_in[3];
    float* out = (float*)d_out;

    unsigned short* Xhi    = (unsigned short*)d_ws;          // 4M  (reused as Ohi)
    unsigned short* Xlo    = Xhi + 4194304;                  // 4M  (reused as Olo)
    unsigned short* WqT_hi = Xlo + 4194304;                  // 3M
    unsigned short* WqT_lo = WqT_hi + 3145728;               // 3M
    unsigned short* WoT_hi = WqT_lo + 3145728;               // 1M
    unsigned short* WoT_lo = WoT_hi + 1048576;               // 1M
    unsigned short* Qb     = WoT_lo + 1048576;               // 4M
    unsigned short* Kb     = Qb + 4194304;                   // 4M
    unsigned short* Vb     = Kb + 4194304;                   // 4M

    convert_x<<<dim3(2048), 256, 0, stream>>>(x, Xhi, Xlo);
    convert_w_T<<<dim3(QKVC_ / 64, 16), 256, 0, stream>>>(w_qkv, WqT_hi, WqT_lo, QKVC_);
    convert_w_T<<<dim3(DIM_ / 64, 16), 256, 0, stream>>>(w_out, WoT_hi, WoT_lo, DIM_);

    qkv_gemm_mfma<<<dim3(QKVC_ / 128, 32), 256, 0, stream>>>(Xhi, Xlo, WqT_hi, WqT_lo, Qb, Kb, Vb);
    rope_kernel<<<dim3(2048), 256, 0, stream>>>(Qb, Kb);
    attn_mfma<<<dim3(N_ / 128, B_ * H_), 512, 0, stream>>>(Qb, Kb, Vb, Xhi, Xlo);
    out_gemm_mfma<<<dim3(DIM_ / 128, 32), 256, 0, stream>>>(Xhi, Xlo, WoT_hi, WoT_lo, b_out, out);
}

// Round 6
// 243.847 us; speedup vs baseline: 1.3084x; 1.3084x over previous
//
#include <hip/hip_runtime.h>
#include <math.h>

#define B_    2
#define N_    2048
#define DIM_  1024
#define H_    16
#define D_    64
#define INNER_ 1024
#define QKVC_ 3072

typedef __attribute__((ext_vector_type(8))) short short8;
typedef __attribute__((ext_vector_type(4))) short short4v;
typedef __attribute__((ext_vector_type(4))) float f32x4;
typedef __attribute__((ext_vector_type(4))) float float4v;

static __device__ __forceinline__ unsigned short f2bf(float f) {
    unsigned int u = __float_as_uint(f);
    u = (u + 0x7fff + ((u >> 16) & 1)) >> 16;   // RNE
    return (unsigned short)u;
}
static __device__ __forceinline__ float bf2f(unsigned short b) {
    return __uint_as_float(((unsigned int)b) << 16);
}

static __device__ __forceinline__ void gload16(const void* g, void* l) {
    __builtin_amdgcn_global_load_lds((__attribute__((address_space(1))) void*)(g),
                                     (__attribute__((address_space(3))) void*)(l),
                                     16, 0, 0);
}

// ---------------------------------------------------------------------------
// convert_x: fp32 (rows x 1024) -> bf16 hi/lo, same layout. 8 elems/thread.
// ---------------------------------------------------------------------------
__global__ __launch_bounds__(256) void convert_x(const float* __restrict__ X,
                                                 unsigned short* __restrict__ Xhi,
                                                 unsigned short* __restrict__ Xlo) {
    int t = blockIdx.x * blockDim.x + threadIdx.x;
    size_t off = (size_t)t * 8;
    float4v a = *(const float4v*)(X + off);
    float4v b = *(const float4v*)(X + off + 4);
    short8 hi, lo;
#pragma unroll
    for (int j = 0; j < 4; ++j) {
        unsigned short h = f2bf(a[j]); hi[j] = (short)h; lo[j] = (short)f2bf(a[j] - bf2f(h));
        unsigned short h2 = f2bf(b[j]); hi[4 + j] = (short)h2; lo[4 + j] = (short)f2bf(b[j] - bf2f(h2));
    }
    *(short8*)(Xhi + off) = hi;
    *(short8*)(Xlo + off) = lo;
}

// ---------------------------------------------------------------------------
// convert_w_T: W fp32 (K=1024 x Nw) -> W^T bf16 hi/lo (Nw x 1024).
// ---------------------------------------------------------------------------
__global__ __launch_bounds__(256) void convert_w_T(const float* __restrict__ W,
                                                   unsigned short* __restrict__ Thi,
                                                   unsigned short* __restrict__ Tlo,
                                                   int Nw) {
    __shared__ unsigned short Shi[64][65];
    __shared__ unsigned short Slo[64][65];
    const int tid = threadIdx.x;
    const int n0 = blockIdx.x * 64;
    const int k0 = blockIdx.y * 64;
#pragma unroll
    for (int l = 0; l < 16; ++l) {
        int idx = tid + l * 256;
        int r = idx >> 6, c = idx & 63;
        float v = W[(size_t)(k0 + r) * Nw + n0 + c];
        unsigned short h = f2bf(v);
        Shi[c][r] = h;
        Slo[c][r] = f2bf(v - bf2f(h));
    }
    __syncthreads();
#pragma unroll
    for (int l = 0; l < 16; ++l) {
        int idx = tid + l * 256;
        int r = idx >> 6, c = idx & 63;
        size_t o = (size_t)(n0 + r) * 1024 + k0 + c;
        Thi[o] = Shi[r][c];
        Tlo[o] = Slo[r][c];
    }
}

// ---------------------------------------------------------------------------
// Split-bf16 GEMM core: C(M x N) = A(M x 1024) * B^T(N x 1024), fp32 acc.
// ---------------------------------------------------------------------------
#define GEMM_STAGE(gA_hi, gA_lo, gB_hi, gB_lo)                                     \
    {                                                                              \
        int c0 = w * 2, c1 = w * 2 + 1;                                            \
        int ra0 = c0 * 16 + (lane >> 2), ra1 = c1 * 16 + (lane >> 2);              \
        int kc = (lane & 3) * 8;                                                   \
        gload16(gA_hi + (size_t)(m0 + ra0) * 1024 + k0 + kc, sAhi + c0 * 512);     \
        gload16(gA_hi + (size_t)(m0 + ra1) * 1024 + k0 + kc, sAhi + c1 * 512);     \
        gload16(gA_lo + (size_t)(m0 + ra0) * 1024 + k0 + kc, sAlo + c0 * 512);     \
        gload16(gA_lo + (size_t)(m0 + ra1) * 1024 + k0 + kc, sAlo + c1 * 512);     \
        gload16(gB_hi + (size_t)(n0 + ra0) * 1024 + k0 + kc, sBhi + c0 * 512);     \
        gload16(gB_hi + (size_t)(n0 + ra1) * 1024 + k0 + kc, sBhi + c1 * 512);     \
        gload16(gB_lo + (size_t)(n0 + ra0) * 1024 + k0 + kc, sBlo + c0 * 512);     \
        gload16(gB_lo + (size_t)(n0 + ra1) * 1024 + k0 + kc, sBlo + c1 * 512);     \
    }

#define GEMM_BODY()                                                                \
    short8 ah[4], al[4], bh[4], bl[4];                                             \
    _Pragma("unroll") for (int f = 0; f < 4; ++f) {                                \
        int offa = (wr + f * 16 + (lane & 15)) * 32 + (lane >> 4) * 8;             \
        ah[f] = *(const short8*)&sAhi[offa];                                       \
        al[f] = *(const short8*)&sAlo[offa];                                       \
        int offb = (wc + f * 16 + (lane & 15)) * 32 + (lane >> 4) * 8;             \
        bh[f] = *(const short8*)&sBhi[offb];                                       \
        bl[f] = *(const short8*)&sBlo[offb];                                       \
    }                                                                              \
    _Pragma("unroll") for (int i = 0; i < 4; ++i)                                  \
        _Pragma("unroll") for (int j = 0; j < 4; ++j) {                            \
            acc[i][j] = __builtin_amdgcn_mfma_f32_16x16x32_bf16(ah[i], bh[j], acc[i][j], 0, 0, 0); \
            acc[i][j] = __builtin_amdgcn_mfma_f32_16x16x32_bf16(al[i], bh[j], acc[i][j], 0, 0, 0); \
            acc[i][j] = __builtin_amdgcn_mfma_f32_16x16x32_bf16(ah[i], bl[j], acc[i][j], 0, 0, 0); \
        }

__global__ __launch_bounds__(256) void qkv_gemm_mfma(const unsigned short* __restrict__ Ahi,
                                                     const unsigned short* __restrict__ Alo,
                                                     const unsigned short* __restrict__ Bhi,
                                                     const unsigned short* __restrict__ Blo,
                                                     unsigned short* __restrict__ Qb,
                                                     unsigned short* __restrict__ Kb,
                                                     unsigned short* __restrict__ Vb) {
    __shared__ __align__(16) unsigned short sAhi[4096], sAlo[4096], sBhi[4096], sBlo[4096];
    const int tid = threadIdx.x;
    const int lane = tid & 63, w = tid >> 6;
    const int wr = (w >> 1) * 64, wc = (w & 1) * 64;
    const int m0 = blockIdx.y * 128, n0 = blockIdx.x * 128;
    f32x4 acc[4][4] = {};

    for (int k0 = 0; k0 < 1024; k0 += 32) {
        GEMM_STAGE(Ahi, Alo, Bhi, Blo);
        __syncthreads();
        GEMM_BODY();
        __syncthreads();
    }

#pragma unroll
    for (int i = 0; i < 4; ++i) {
        int mbase = m0 + wr + i * 16 + (lane >> 4) * 4;
#pragma unroll
        for (int j = 0; j < 4; ++j) {
            int col = n0 + wc + j * 16 + (lane & 15);
            int seg = col >> 10;
            int wcol = col & 1023;
            int h = wcol >> 6, dd = wcol & 63;
            unsigned short* dst = (seg == 0) ? Qb : (seg == 1 ? Kb : Vb);
#pragma unroll
            for (int r = 0; r < 4; ++r) {
                int row = mbase + r;
                int b = row >> 11, n = row & (N_ - 1);
                dst[((size_t)(b * H_ + h) * N_ + n) * D_ + dd] = f2bf(acc[i][j][r]);
            }
        }
    }
}

__global__ __launch_bounds__(256) void out_gemm_mfma(const unsigned short* __restrict__ Ahi,
                                                     const unsigned short* __restrict__ Alo,
                                                     const unsigned short* __restrict__ Bhi,
                                                     const unsigned short* __restrict__ Blo,
                                                     const float* __restrict__ bias,
                                                     float* __restrict__ C) {
    __shared__ __align__(16) unsigned short sAhi[4096], sAlo[4096], sBhi[4096], sBlo[4096];
    const int tid = threadIdx.x;
    const int lane = tid & 63, w = tid >> 6;
    const int wr = (w >> 1) * 64, wc = (w & 1) * 64;
    const int m0 = blockIdx.y * 128, n0 = blockIdx.x * 128;
    f32x4 acc[4][4] = {};

    for (int k0 = 0; k0 < 1024; k0 += 32) {
        GEMM_STAGE(Ahi, Alo, Bhi, Blo);
        __syncthreads();
        GEMM_BODY();
        __syncthreads();
    }

#pragma unroll
    for (int i = 0; i < 4; ++i) {
        int mbase = m0 + wr + i * 16 + (lane >> 4) * 4;
#pragma unroll
        for (int j = 0; j < 4; ++j) {
            int col = n0 + wc + j * 16 + (lane & 15);
            float bv = bias[col];
#pragma unroll
            for (int r = 0; r < 4; ++r)
                C[(size_t)(mbase + r) * DIM_ + col] = acc[i][j][r] + bv;
        }
    }
}

// ---------------------------------------------------------------------------
// RoPE in-place on bf16 Q and K. Q pre-scaled by 0.125*log2(e) so the
// attention softmax runs in exp2 domain with no per-element scale.
// ---------------------------------------------------------------------------
#define QSCALE 0.180336879963f   // 0.125 * log2(e)
__global__ void rope_kernel(unsigned short* __restrict__ Qb,
                            unsigned short* __restrict__ Kb) {
    const int total = B_ * H_ * N_ * (D_ / 2);
    for (int p = blockIdx.x * blockDim.x + threadIdx.x; p < total;
         p += gridDim.x * blockDim.x) {
        int d2 = p & 31;
        int rest = p >> 5;
        int n = rest & (N_ - 1);
        size_t off = (size_t)rest * D_ + 2 * d2;
        float freq = powf(10000.0f, -(float)d2 * (1.0f / 32.0f));
        float ang = (float)n * freq;
        float s, c;
        sincosf(ang, &s, &c);

        unsigned int uq = *(unsigned int*)(Qb + off);
        float q0 = __uint_as_float(uq << 16);
        float q1 = __uint_as_float(uq & 0xffff0000u);
        *(unsigned int*)(Qb + off) =
            (unsigned int)f2bf((q0 * c - q1 * s) * QSCALE) |
            ((unsigned int)f2bf((q1 * c + q0 * s) * QSCALE) << 16);

        unsigned int uk = *(unsigned int*)(Kb + off);
        float k0 = __uint_as_float(uk << 16);
        float k1 = __uint_as_float(uk & 0xffff0000u);
        *(unsigned int*)(Kb + off) = (unsigned int)f2bf(k0 * c - k1 * s) |
                                     ((unsigned int)f2bf(k1 * c + k0 * s) << 16);
    }
}

// ---------------------------------------------------------------------------
// Flash attention v4: K staged in LDS (global_load_lds, dbuf, XOR-swizzled
// reads); V dbuf transposed in LDS; in-register P (swapped QK); one barrier
// per tile; XCD-aware block remap (each XCD owns 4 heads).
// ---------------------------------------------------------------------------
#define PADV 68
#define NT   (N_ / 64)
__global__ __launch_bounds__(512, 4) void attn_mfma(const unsigned short* __restrict__ Qb,
                                                    const unsigned short* __restrict__ Kb,
                                                    const unsigned short* __restrict__ Vb,
                                                    unsigned short* __restrict__ Ohi,
                                                    unsigned short* __restrict__ Olo) {
    __shared__ __align__(16) unsigned short Ks[2 * 64 * 64];    // K rows, XOR-swz cols
    __shared__ __align__(16) unsigned short Vt[2][64][PADV];    // V^T: [d][kv]
    const int tid = threadIdx.x;
    const int w = tid >> 6;
    const int l = tid & 63;
    const int lr = l & 15, lg = l >> 4;

    // XCD remap: flat = bh*16+qt dispatch order -> xcd x owns bh in [4x,4x+4)
    const int f = blockIdx.y * gridDim.x + blockIdx.x;          // 0..511
    const int x = f & 7, g = f >> 3;
    const int bh = x * 4 + (g >> 4);
    const int q0 = (g & 15) * 128;
    const size_t base = (size_t)bh * N_ * D_;

    // K staging coords: thread stages 16B slot (srow, scg) from pre-swizzled src
    const int srow = tid >> 3;           // 0..63
    const int scg  = tid & 7;
    const int gcg  = scg ^ (srow & 7);   // involution
    const unsigned short* ksrc = Kb + base + (size_t)srow * D_ + gcg * 8;
    unsigned short* kdst = Ks + w * 512; // wave-uniform; HW adds lane*16B

    // V staging coords
    const int sd0 = (tid & 15) * 4;
    const int skv = (tid >> 4) * 2;

    // Q as B-operand: lane holds col q=lr, k d=lg*8+j (+32h)
    const unsigned short* qrow = Qb + base + (size_t)(q0 + w * 16 + lr) * D_ + lg * 8;
    const short8 qf0 = *(const short8*)qrow;
    const short8 qf1 = *(const short8*)(qrow + 32);

    f32x4 oacc[4] = {};                 // [dt]: q=lg*4+r, d=dt*16+lr
    float mrow = -1e30f, lsum = 0.f;    // per-lane state for q-row lr

    // ---- prologue: stage tile 0 (K via gload_lds, V via regs) ----
    gload16(ksrc, kdst);
    {
        short4v r0 = *(const short4v*)(Vb + base + (size_t)(skv + 0) * D_ + sd0);
        short4v r1 = *(const short4v*)(Vb + base + (size_t)(skv + 1) * D_ + sd0);
#pragma unroll
        for (int j = 0; j < 4; ++j) {
            unsigned int pk = (unsigned int)(unsigned short)r0[j] |
                              ((unsigned int)(unsigned short)r1[j] << 16);
            *(unsigned int*)&Vt[0][sd0 + j][skv] = pk;
        }
    }

    for (int ti = 0; ti < NT; ++ti) {
        const int cur = ti & 1, nxt = cur ^ 1;
        __syncthreads();    // tile ti staged (compiler drains vmcnt before barrier)

        // ---- issue tile ti+1 staging early (T14) ----
        short4v n0v = {}, n1v = {};
        if (ti + 1 < NT) {
            gload16(ksrc + (size_t)(ti + 1) * 64 * D_, kdst + nxt * 4096);
            const unsigned short* nsrc = Vb + base + (size_t)((ti + 1) * 64 + skv) * D_ + sd0;
            n0v = *(const short4v*)nsrc;
            n1v = *(const short4v*)(nsrc + D_);
        }

        // ---- QK(ti): S^T = K.Q^T, K A-frags from swizzled LDS ----
        f32x4 sacc[4] = {};
        __builtin_amdgcn_s_setprio(1);
#pragma unroll
        for (int t = 0; t < 4; ++t) {
            int row = t * 16 + lr;
            int swz = (row & 7);
            const unsigned short* kr = Ks + cur * 4096 + row * 64;
            short8 kf0 = *(const short8*)(kr + (lg ^ swz) * 8);
            short8 kf1 = *(const short8*)(kr + ((lg + 4) ^ swz) * 8);
            sacc[t] = __builtin_amdgcn_mfma_f32_16x16x32_bf16(kf0, qf0, sacc[t], 0, 0, 0);
            sacc[t] = __builtin_amdgcn_mfma_f32_16x16x32_bf16(kf1, qf1, sacc[t], 0, 0, 0);
        }
        __builtin_amdgcn_s_setprio(0);

        // ---- softmax (exp2 domain); lane owns 16 kv of q-row lr ----
        float tm = -1e30f;
#pragma unroll
        for (int t = 0; t < 4; ++t)
#pragma unroll
            for (int r = 0; r < 4; ++r) tm = fmaxf(tm, sacc[t][r]);
        tm = fmaxf(tm, __shfl_xor(tm, 16));
        tm = fmaxf(tm, __shfl_xor(tm, 32));
        float nm = fmaxf(mrow, tm);
        float al = __builtin_amdgcn_exp2f(mrow - nm);
        mrow = nm;

        short8 pa[2];
        float ps = 0.f;
#pragma unroll
        for (int t = 0; t < 4; ++t)
#pragma unroll
            for (int r = 0; r < 4; ++r) {
                float e = __builtin_amdgcn_exp2f(sacc[t][r] - nm);
                ps += e;
                pa[t >> 1][(t & 1) * 4 + r] = (short)f2bf(e);
            }
        ps += __shfl_xor(ps, 16);
        ps += __shfl_xor(ps, 32);
        lsum = lsum * al + ps;

        // ---- O rescale + PV(ti) ----
#pragma unroll
        for (int r = 0; r < 4; ++r) {
            float alq = __shfl(al, lg * 4 + r);
#pragma unroll
            for (int dt = 0; dt < 4; ++dt) oacc[dt][r] *= alq;
        }
        __builtin_amdgcn_s_setprio(1);
#pragma unroll
        for (int m2 = 0; m2 < 2; ++m2)
#pragma unroll
            for (int dt = 0; dt < 4; ++dt) {
                short4v v0 = *(const short4v*)&Vt[cur][dt * 16 + lr][m2 * 32 + lg * 4];
                short4v v1 = *(const short4v*)&Vt[cur][dt * 16 + lr][m2 * 32 + 16 + lg * 4];
                short8 vb = {v0[0], v0[1], v0[2], v0[3], v1[0], v1[1], v1[2], v1[3]};
                oacc[dt] = __builtin_amdgcn_mfma_f32_16x16x32_bf16(pa[m2], vb, oacc[dt], 0, 0, 0);
            }
        __builtin_amdgcn_s_setprio(0);

        // ---- commit V(ti+1) ----
        if (ti + 1 < NT) {
#pragma unroll
            for (int j = 0; j < 4; ++j) {
                unsigned int pk = (unsigned int)(unsigned short)n0v[j] |
                                  ((unsigned int)(unsigned short)n1v[j] << 16);
                *(unsigned int*)&Vt[nxt][sd0 + j][skv] = pk;
            }
        }
    }

    // ---- epilogue ----
    int b = bh >> 4, h = bh & 15;
#pragma unroll
    for (int r = 0; r < 4; ++r) {
        float ls = __shfl(lsum, lg * 4 + r);
        float inv = 1.0f / ls;
        size_t orow = ((size_t)b * N_ + q0 + w * 16 + lg * 4 + r) * INNER_ + h * 64 + lr;
#pragma unroll
        for (int dt = 0; dt < 4; ++dt) {
            float o = oacc[dt][r] * inv;
            unsigned short hi = f2bf(o);
            Ohi[orow + 16 * dt] = hi;
            Olo[orow + 16 * dt] = f2bf(o - bf2f(hi));
        }
    }
}

// ---------------------------------------------------------------------------
extern "C" void kernel_launch(void* const* d_in, const int* in_sizes, int n_in,
                              void* d_out, int out_size, void* d_ws, size_t ws_size,
                              hipStream_t stream) {
    const float* x     = (const float*)d_in[0];
    const float* w_qkv = (const float*)d_in[1];
    const float* w_out = (const float*)d_in[2];
    const float* b_out = (const float*)d_in[3];
    float* out = (float*)d_out;

    unsigned short* Xhi    = (unsigned short*)d_ws;          // 4M  (reused as Ohi)
    unsigned short* Xlo    = Xhi + 4194304;                  // 4M  (reused as Olo)
    unsigned short* WqT_hi = Xlo + 4194304;                  // 3M
    unsigned short* WqT_lo = WqT_hi + 3145728;               // 3M
    unsigned short* WoT_hi = WqT_lo + 3145728;               // 1M
    unsigned short* WoT_lo = WoT_hi + 1048576;               // 1M
    unsigned short* Qb     = WoT_lo + 1048576;               // 4M
    unsigned short* Kb     = Qb + 4194304;                   // 4M
    unsigned short* Vb     = Kb + 4194304;                   // 4M

    convert_x<<<dim3(2048), 256, 0, stream>>>(x, Xhi, Xlo);
    convert_w_T<<<dim3(QKVC_ / 64, 16), 256, 0, stream>>>(w_qkv, WqT_hi, WqT_lo, QKVC_);
    convert_w_T<<<dim3(DIM_ / 64, 16), 256, 0, stream>>>(w_out, WoT_hi, WoT_lo, DIM_);

    qkv_gemm_mfma<<<dim3(QKVC_ / 128, 32), 256, 0, stream>>>(Xhi, Xlo, WqT_hi, WqT_lo, Qb, Kb, Vb);
    rope_kernel<<<dim3(2048), 256, 0, stream>>>(Qb, Kb);
    attn_mfma<<<dim3(N_ / 128, B_ * H_), 512, 0, stream>>>(Qb, Kb, Vb, Xhi, Xlo);
    out_gemm_mfma<<<dim3(DIM_ / 128, 32), 256, 0, stream>>>(Xhi, Xlo, WoT_hi, WoT_lo, b_out, out);
}

// Round 7
// 151.928 us; speedup vs baseline: 2.1001x; 1.6050x over previous
//
#include <hip/hip_runtime.h>
#include <math.h>

#define B_    2
#define N_    2048
#define DIM_  1024
#define H_    16
#define D_    64
#define INNER_ 1024
#define QKVC_ 3072

typedef __attribute__((ext_vector_type(8))) short short8;
typedef __attribute__((ext_vector_type(4))) short short4v;
typedef __attribute__((ext_vector_type(4))) float f32x4;
typedef __attribute__((ext_vector_type(4))) float float4v;
typedef _Float16 half8 __attribute__((ext_vector_type(8)));

union h8u { short8 s; half8 h; };
static __device__ __forceinline__ half8 s2h(short8 s) { h8u u; u.s = s; return u.h; }

static __device__ __forceinline__ unsigned short f2h(float f) {
    _Float16 h = (_Float16)f;
    unsigned short u;
    __builtin_memcpy(&u, &h, 2);
    return u;
}
static __device__ __forceinline__ float h2f(unsigned short u) {
    _Float16 h;
    __builtin_memcpy(&h, &u, 2);
    return (float)h;
}

static __device__ __forceinline__ void gload16(const void* g, void* l) {
    __builtin_amdgcn_global_load_lds((__attribute__((address_space(1))) void*)(g),
                                     (__attribute__((address_space(3))) void*)(l),
                                     16, 0, 0);
}

// ---------------------------------------------------------------------------
// convert_x: fp32 (4096 x 1024) -> fp16, same layout. 8 elems/thread.
// ---------------------------------------------------------------------------
__global__ __launch_bounds__(256) void convert_x(const float* __restrict__ X,
                                                 unsigned short* __restrict__ Xh) {
    int t = blockIdx.x * blockDim.x + threadIdx.x;
    size_t off = (size_t)t * 8;
    float4v a = *(const float4v*)(X + off);
    float4v b = *(const float4v*)(X + off + 4);
    short8 o;
#pragma unroll
    for (int j = 0; j < 4; ++j) {
        o[j]     = (short)f2h(a[j]);
        o[4 + j] = (short)f2h(b[j]);
    }
    *(short8*)(Xh + off) = o;
}

// ---------------------------------------------------------------------------
// convert_w_T: W fp32 (K=1024 x Nw) -> W^T fp16 (Nw x 1024).
// ---------------------------------------------------------------------------
__global__ __launch_bounds__(256) void convert_w_T(const float* __restrict__ W,
                                                   unsigned short* __restrict__ Th,
                                                   int Nw) {
    __shared__ unsigned short Sh[64][65];
    const int tid = threadIdx.x;
    const int n0 = blockIdx.x * 64;
    const int k0 = blockIdx.y * 64;
#pragma unroll
    for (int l = 0; l < 16; ++l) {
        int idx = tid + l * 256;
        int r = idx >> 6, c = idx & 63;
        Sh[c][r] = f2h(W[(size_t)(k0 + r) * Nw + n0 + c]);
    }
    __syncthreads();
#pragma unroll
    for (int l = 0; l < 16; ++l) {
        int idx = tid + l * 256;
        int r = idx >> 6, c = idx & 63;
        Th[(size_t)(n0 + r) * 1024 + k0 + c] = Sh[r][c];
    }
}

// ---------------------------------------------------------------------------
// fp16 GEMM core: C(M x N) = A(M x 1024) * B^T(N x 1024), fp32 acc.
// 128x128 tile, BK=32, 4 waves (2x2), 16 MFMA / K-step.
// ---------------------------------------------------------------------------
#define GEMM_STAGE_H(gA, gB)                                                       \
    {                                                                              \
        int rr0 = w * 32 + (lane >> 2), rr1 = w * 32 + 16 + (lane >> 2);           \
        int kc = (lane & 3) * 8;                                                   \
        gload16(gA + (size_t)(m0 + rr0) * 1024 + k0 + kc, sA + (w * 32) * 32);     \
        gload16(gA + (size_t)(m0 + rr1) * 1024 + k0 + kc, sA + (w * 32 + 16) * 32);\
        gload16(gB + (size_t)(n0 + rr0) * 1024 + k0 + kc, sB + (w * 32) * 32);     \
        gload16(gB + (size_t)(n0 + rr1) * 1024 + k0 + kc, sB + (w * 32 + 16) * 32);\
    }

#define GEMM_BODY_H()                                                              \
    half8 af[4], bf[4];                                                            \
    _Pragma("unroll") for (int f = 0; f < 4; ++f) {                                \
        af[f] = s2h(*(const short8*)&sA[(wr + f * 16 + (lane & 15)) * 32 + (lane >> 4) * 8]); \
        bf[f] = s2h(*(const short8*)&sB[(wc + f * 16 + (lane & 15)) * 32 + (lane >> 4) * 8]); \
    }                                                                              \
    _Pragma("unroll") for (int i = 0; i < 4; ++i)                                  \
        _Pragma("unroll") for (int j = 0; j < 4; ++j)                              \
            acc[i][j] = __builtin_amdgcn_mfma_f32_16x16x32_f16(af[i], bf[j], acc[i][j], 0, 0, 0);

__global__ __launch_bounds__(256) void qkv_gemm_mfma(const unsigned short* __restrict__ Ah,
                                                     const unsigned short* __restrict__ Bh,
                                                     unsigned short* __restrict__ Qh,
                                                     unsigned short* __restrict__ Kh,
                                                     unsigned short* __restrict__ Vh) {
    __shared__ __align__(16) unsigned short sA[4096], sB[4096];
    const int tid = threadIdx.x;
    const int lane = tid & 63, w = tid >> 6;
    const int wr = (w >> 1) * 64, wc = (w & 1) * 64;
    const int m0 = blockIdx.y * 128, n0 = blockIdx.x * 128;
    f32x4 acc[4][4] = {};

    for (int k0 = 0; k0 < 1024; k0 += 32) {
        GEMM_STAGE_H(Ah, Bh);
        __syncthreads();
        GEMM_BODY_H();
        __syncthreads();
    }

#pragma unroll
    for (int i = 0; i < 4; ++i) {
        int mbase = m0 + wr + i * 16 + (lane >> 4) * 4;
#pragma unroll
        for (int j = 0; j < 4; ++j) {
            int col = n0 + wc + j * 16 + (lane & 15);
            int seg = col >> 10;
            int wcol = col & 1023;
            int h = wcol >> 6, dd = wcol & 63;
            unsigned short* dst = (seg == 0) ? Qh : (seg == 1 ? Kh : Vh);
#pragma unroll
            for (int r = 0; r < 4; ++r) {
                int row = mbase + r;
                int b = row >> 11, n = row & (N_ - 1);
                dst[((size_t)(b * H_ + h) * N_ + n) * D_ + dd] = f2h(acc[i][j][r]);
            }
        }
    }
}

__global__ __launch_bounds__(256) void out_gemm_mfma(const unsigned short* __restrict__ Ah,
                                                     const unsigned short* __restrict__ Bh,
                                                     const float* __restrict__ bias,
                                                     float* __restrict__ C) {
    __shared__ __align__(16) unsigned short sA[4096], sB[4096];
    const int tid = threadIdx.x;
    const int lane = tid & 63, w = tid >> 6;
    const int wr = (w >> 1) * 64, wc = (w & 1) * 64;
    const int m0 = blockIdx.y * 128, n0 = blockIdx.x * 128;
    f32x4 acc[4][4] = {};

    for (int k0 = 0; k0 < 1024; k0 += 32) {
        GEMM_STAGE_H(Ah, Bh);
        __syncthreads();
        GEMM_BODY_H();
        __syncthreads();
    }

#pragma unroll
    for (int i = 0; i < 4; ++i) {
        int mbase = m0 + wr + i * 16 + (lane >> 4) * 4;
#pragma unroll
        for (int j = 0; j < 4; ++j) {
            int col = n0 + wc + j * 16 + (lane & 15);
            float bv = bias[col];
#pragma unroll
            for (int r = 0; r < 4; ++r)
                C[(size_t)(mbase + r) * DIM_ + col] = acc[i][j][r] + bv;
        }
    }
}

// ---------------------------------------------------------------------------
// RoPE in-place on fp16 Q and K. Q pre-scaled by 0.125*log2(e) so the
// attention softmax runs in exp2 domain with no per-element scale.
// ---------------------------------------------------------------------------
#define QSCALE 0.180336879963f   // 0.125 * log2(e)
__global__ void rope_kernel(unsigned short* __restrict__ Qh,
                            unsigned short* __restrict__ Kh) {
    const int total = B_ * H_ * N_ * (D_ / 2);
    for (int p = blockIdx.x * blockDim.x + threadIdx.x; p < total;
         p += gridDim.x * blockDim.x) {
        int d2 = p & 31;
        int rest = p >> 5;
        int n = rest & (N_ - 1);
        size_t off = (size_t)rest * D_ + 2 * d2;
        float freq = powf(10000.0f, -(float)d2 * (1.0f / 32.0f));
        float ang = (float)n * freq;
        float s, c;
        sincosf(ang, &s, &c);

        unsigned int uq = *(unsigned int*)(Qh + off);
        float q0 = h2f((unsigned short)(uq & 0xffff));
        float q1 = h2f((unsigned short)(uq >> 16));
        *(unsigned int*)(Qh + off) =
            (unsigned int)f2h((q0 * c - q1 * s) * QSCALE) |
            ((unsigned int)f2h((q1 * c + q0 * s) * QSCALE) << 16);

        unsigned int uk = *(unsigned int*)(Kh + off);
        float k0 = h2f((unsigned short)(uk & 0xffff));
        float k1 = h2f((unsigned short)(uk >> 16));
        *(unsigned int*)(Kh + off) = (unsigned int)f2h(k0 * c - k1 * s) |
                                     ((unsigned int)f2h(k1 * c + k0 * s) << 16);
    }
}

// ---------------------------------------------------------------------------
// Flash attention (fp16 operands, fp32 softmax/accum): K staged in LDS
// (global_load_lds, dbuf, XOR-swizzled reads); V dbuf transposed in LDS;
// in-register P (swapped QK); one barrier per tile; XCD-aware block remap.
// ---------------------------------------------------------------------------
#define PADV 68
#define NT   (N_ / 64)
__global__ __launch_bounds__(512, 4) void attn_mfma(const unsigned short* __restrict__ Qh,
                                                    const unsigned short* __restrict__ Kh,
                                                    const unsigned short* __restrict__ Vh,
                                                    unsigned short* __restrict__ Oh) {
    __shared__ __align__(16) unsigned short Ks[2 * 64 * 64];    // K rows, XOR-swz cols
    __shared__ __align__(16) unsigned short Vt[2][64][PADV];    // V^T: [d][kv]
    const int tid = threadIdx.x;
    const int w = tid >> 6;
    const int l = tid & 63;
    const int lr = l & 15, lg = l >> 4;

    // XCD remap: xcd x owns bh in [4x, 4x+4)
    const int f = blockIdx.y * gridDim.x + blockIdx.x;          // 0..511
    const int x = f & 7, g = f >> 3;
    const int bh = x * 4 + (g >> 4);
    const int q0 = (g & 15) * 128;
    const size_t base = (size_t)bh * N_ * D_;

    // K staging coords (pre-swizzled global source, linear LDS dest)
    const int srow = tid >> 3;
    const int scg  = tid & 7;
    const int gcg  = scg ^ (srow & 7);
    const unsigned short* ksrc = Kh + base + (size_t)srow * D_ + gcg * 8;
    unsigned short* kdst = Ks + w * 512;

    // V staging coords
    const int sd0 = (tid & 15) * 4;
    const int skv = (tid >> 4) * 2;

    // Q as B-operand: lane holds col q=lr, k d=lg*8+j (+32h)
    const unsigned short* qrow = Qh + base + (size_t)(q0 + w * 16 + lr) * D_ + lg * 8;
    const half8 qf0 = s2h(*(const short8*)qrow);
    const half8 qf1 = s2h(*(const short8*)(qrow + 32));

    f32x4 oacc[4] = {};                 // [dt]: q=lg*4+r, d=dt*16+lr
    float mrow = -1e30f, lsum = 0.f;

    // ---- prologue: stage tile 0 ----
    gload16(ksrc, kdst);
    {
        short4v r0 = *(const short4v*)(Vh + base + (size_t)(skv + 0) * D_ + sd0);
        short4v r1 = *(const short4v*)(Vh + base + (size_t)(skv + 1) * D_ + sd0);
#pragma unroll
        for (int j = 0; j < 4; ++j) {
            unsigned int pk = (unsigned int)(unsigned short)r0[j] |
                              ((unsigned int)(unsigned short)r1[j] << 16);
            *(unsigned int*)&Vt[0][sd0 + j][skv] = pk;
        }
    }

    for (int ti = 0; ti < NT; ++ti) {
        const int cur = ti & 1, nxt = cur ^ 1;
        __syncthreads();

        // ---- issue tile ti+1 staging early ----
        short4v n0v = {}, n1v = {};
        if (ti + 1 < NT) {
            gload16(ksrc + (size_t)(ti + 1) * 64 * D_, kdst + nxt * 4096);
            const unsigned short* nsrc = Vh + base + (size_t)((ti + 1) * 64 + skv) * D_ + sd0;
            n0v = *(const short4v*)nsrc;
            n1v = *(const short4v*)(nsrc + D_);
        }

        // ---- QK(ti): S^T = K.Q^T, K A-frags from swizzled LDS ----
        f32x4 sacc[4] = {};
        __builtin_amdgcn_s_setprio(1);
#pragma unroll
        for (int t = 0; t < 4; ++t) {
            int row = t * 16 + lr;
            int swz = (row & 7);
            const unsigned short* kr = Ks + cur * 4096 + row * 64;
            half8 kf0 = s2h(*(const short8*)(kr + (lg ^ swz) * 8));
            half8 kf1 = s2h(*(const short8*)(kr + ((lg + 4) ^ swz) * 8));
            sacc[t] = __builtin_amdgcn_mfma_f32_16x16x32_f16(kf0, qf0, sacc[t], 0, 0, 0);
            sacc[t] = __builtin_amdgcn_mfma_f32_16x16x32_f16(kf1, qf1, sacc[t], 0, 0, 0);
        }
        __builtin_amdgcn_s_setprio(0);

        // ---- softmax (exp2 domain); lane owns 16 kv of q-row lr ----
        float tm = -1e30f;
#pragma unroll
        for (int t = 0; t < 4; ++t)
#pragma unroll
            for (int r = 0; r < 4; ++r) tm = fmaxf(tm, sacc[t][r]);
        tm = fmaxf(tm, __shfl_xor(tm, 16));
        tm = fmaxf(tm, __shfl_xor(tm, 32));
        float nm = fmaxf(mrow, tm);
        float al = __builtin_amdgcn_exp2f(mrow - nm);
        mrow = nm;

        short8 pa[2];
        float ps = 0.f;
#pragma unroll
        for (int t = 0; t < 4; ++t)
#pragma unroll
            for (int r = 0; r < 4; ++r) {
                float e = __builtin_amdgcn_exp2f(sacc[t][r] - nm);
                ps += e;
                pa[t >> 1][(t & 1) * 4 + r] = (short)f2h(e);
            }
        ps += __shfl_xor(ps, 16);
        ps += __shfl_xor(ps, 32);
        lsum = lsum * al + ps;

        // ---- O rescale + PV(ti) ----
#pragma unroll
        for (int r = 0; r < 4; ++r) {
            float alq = __shfl(al, lg * 4 + r);
#pragma unroll
            for (int dt = 0; dt < 4; ++dt) oacc[dt][r] *= alq;
        }
        __builtin_amdgcn_s_setprio(1);
#pragma unroll
        for (int m2 = 0; m2 < 2; ++m2)
#pragma unroll
            for (int dt = 0; dt < 4; ++dt) {
                short4v v0 = *(const short4v*)&Vt[cur][dt * 16 + lr][m2 * 32 + lg * 4];
                short4v v1 = *(const short4v*)&Vt[cur][dt * 16 + lr][m2 * 32 + 16 + lg * 4];
                short8 vb = {v0[0], v0[1], v0[2], v0[3], v1[0], v1[1], v1[2], v1[3]};
                oacc[dt] = __builtin_amdgcn_mfma_f32_16x16x32_f16(s2h(pa[m2]), s2h(vb), oacc[dt], 0, 0, 0);
            }
        __builtin_amdgcn_s_setprio(0);

        // ---- commit V(ti+1) ----
        if (ti + 1 < NT) {
#pragma unroll
            for (int j = 0; j < 4; ++j) {
                unsigned int pk = (unsigned int)(unsigned short)n0v[j] |
                                  ((unsigned int)(unsigned short)n1v[j] << 16);
                *(unsigned int*)&Vt[nxt][sd0 + j][skv] = pk;
            }
        }
    }

    // ---- epilogue ----
    int b = bh >> 4, h = bh & 15;
#pragma unroll
    for (int r = 0; r < 4; ++r) {
        float ls = __shfl(lsum, lg * 4 + r);
        float inv = 1.0f / ls;
        size_t orow = ((size_t)b * N_ + q0 + w * 16 + lg * 4 + r) * INNER_ + h * 64 + lr;
#pragma unroll
        for (int dt = 0; dt < 4; ++dt)
            Oh[orow + 16 * dt] = f2h(oacc[dt][r] * inv);
    }
}

// ---------------------------------------------------------------------------
extern "C" void kernel_launch(void* const* d_in, const int* in_sizes, int n_in,
                              void* d_out, int out_size, void* d_ws, size_t ws_size,
                              hipStream_t stream) {
    const float* x     = (const float*)d_in[0];
    const float* w_qkv = (const float*)d_in[1];
    const float* w_out = (const float*)d_in[2];
    const float* b_out = (const float*)d_in[3];
    float* out = (float*)d_out;

    unsigned short* Xh  = (unsigned short*)d_ws;     // 4M elems (reused as Oh)
    unsigned short* WqT = Xh + 4194304;              // 3M
    unsigned short* WoT = WqT + 3145728;             // 1M
    unsigned short* Qh  = WoT + 1048576;             // 4M
    unsigned short* Kh  = Qh + 4194304;              // 4M
    unsigned short* Vh  = Kh + 4194304;              // 4M

    convert_x<<<dim3(2048), 256, 0, stream>>>(x, Xh);
    convert_w_T<<<dim3(QKVC_ / 64, 16), 256, 0, stream>>>(w_qkv, WqT, QKVC_);
    convert_w_T<<<dim3(DIM_ / 64, 16), 256, 0, stream>>>(w_out, WoT, DIM_);

    qkv_gemm_mfma<<<dim3(QKVC_ / 128, 32), 256, 0, stream>>>(Xh, WqT, Qh, Kh, Vh);
    rope_kernel<<<dim3(2048), 256, 0, stream>>>(Qh, Kh);
    attn_mfma<<<dim3(N_ / 128, B_ * H_), 512, 0, stream>>>(Qh, Kh, Vh, Xh);
    out_gemm_mfma<<<dim3(DIM_ / 128, 32), 256, 0, stream>>>(Xh, WoT, b_out, out);
}

// Round 9
// 143.247 us; speedup vs baseline: 2.2273x; 1.0606x over previous
//
#include <hip/hip_runtime.h>
#include <math.h>

#define B_    2
#define N_    2048
#define DIM_  1024
#define H_    16
#define D_    64
#define INNER_ 1024
#define QKVC_ 3072

typedef __attribute__((ext_vector_type(8))) short short8;
typedef __attribute__((ext_vector_type(4))) short short4v;
typedef __attribute__((ext_vector_type(4))) float f32x4;
typedef __attribute__((ext_vector_type(4))) float float4v;
typedef _Float16 half8 __attribute__((ext_vector_type(8)));
typedef __fp16 fp16v2 __attribute__((ext_vector_type(2)));

union h8u { short8 s; half8 h; fp16v2 h2[4]; };
static __device__ __forceinline__ half8 s2h(short8 s) { h8u u; u.s = s; return u.h; }

static __device__ __forceinline__ unsigned short f2h(float f) {
    _Float16 h = (_Float16)f;
    unsigned short u;
    __builtin_memcpy(&u, &h, 2);
    return u;
}
static __device__ __forceinline__ float h2f(unsigned short u) {
    _Float16 h;
    __builtin_memcpy(&h, &u, 2);
    return (float)h;
}

static __device__ __forceinline__ void gload16(const void* g, void* l) {
    __builtin_amdgcn_global_load_lds((__attribute__((address_space(1))) void*)(g),
                                     (__attribute__((address_space(3))) void*)(l),
                                     16, 0, 0);
}

// ---------------------------------------------------------------------------
// convert_x: fp32 (4096 x 1024) -> fp16, same layout. 8 elems/thread.
// ---------------------------------------------------------------------------
__global__ __launch_bounds__(256) void convert_x(const float* __restrict__ X,
                                                 unsigned short* __restrict__ Xh) {
    int t = blockIdx.x * blockDim.x + threadIdx.x;
    size_t off = (size_t)t * 8;
    float4v a = *(const float4v*)(X + off);
    float4v b = *(const float4v*)(X + off + 4);
    short8 o;
#pragma unroll
    for (int j = 0; j < 4; ++j) {
        o[j]     = (short)f2h(a[j]);
        o[4 + j] = (short)f2h(b[j]);
    }
    *(short8*)(Xh + off) = o;
}

// ---------------------------------------------------------------------------
// convert_w_T: W fp32 (K=1024 x Nw) -> W^T fp16 (Nw x 1024).
// ---------------------------------------------------------------------------
__global__ __launch_bounds__(256) void convert_w_T(const float* __restrict__ W,
                                                   unsigned short* __restrict__ Th,
                                                   int Nw) {
    __shared__ unsigned short Sh[64][65];
    const int tid = threadIdx.x;
    const int n0 = blockIdx.x * 64;
    const int k0 = blockIdx.y * 64;
#pragma unroll
    for (int l = 0; l < 16; ++l) {
        int idx = tid + l * 256;
        int r = idx >> 6, c = idx & 63;
        Sh[c][r] = f2h(W[(size_t)(k0 + r) * Nw + n0 + c]);
    }
    __syncthreads();
#pragma unroll
    for (int l = 0; l < 16; ++l) {
        int idx = tid + l * 256;
        int r = idx >> 6, c = idx & 63;
        Th[(size_t)(n0 + r) * 1024 + k0 + c] = Sh[r][c];
    }
}

// ---------------------------------------------------------------------------
// fp16 GEMM core: C(M x N) = A(M x 1024) * B^T(N x 1024), fp32 acc.
// ---------------------------------------------------------------------------
#define GEMM_STAGE_H(gA, gB)                                                       \
    {                                                                              \
        int rr0 = w * 32 + (lane >> 2), rr1 = w * 32 + 16 + (lane >> 2);           \
        int kc = (lane & 3) * 8;                                                   \
        gload16(gA + (size_t)(m0 + rr0) * 1024 + k0 + kc, sA + (w * 32) * 32);     \
        gload16(gA + (size_t)(m0 + rr1) * 1024 + k0 + kc, sA + (w * 32 + 16) * 32);\
        gload16(gB + (size_t)(n0 + rr0) * 1024 + k0 + kc, sB + (w * 32) * 32);     \
        gload16(gB + (size_t)(n0 + rr1) * 1024 + k0 + kc, sB + (w * 32 + 16) * 32);\
    }

#define GEMM_BODY_H()                                                              \
    half8 af[4], bf[4];                                                            \
    _Pragma("unroll") for (int f = 0; f < 4; ++f) {                                \
        af[f] = s2h(*(const short8*)&sA[(wr + f * 16 + (lane & 15)) * 32 + (lane >> 4) * 8]); \
        bf[f] = s2h(*(const short8*)&sB[(wc + f * 16 + (lane & 15)) * 32 + (lane >> 4) * 8]); \
    }                                                                              \
    _Pragma("unroll") for (int i = 0; i < 4; ++i)                                  \
        _Pragma("unroll") for (int j = 0; j < 4; ++j)                              \
            acc[i][j] = __builtin_amdgcn_mfma_f32_16x16x32_f16(af[i], bf[j], acc[i][j], 0, 0, 0);

__global__ __launch_bounds__(256) void qkv_gemm_mfma(const unsigned short* __restrict__ Ah,
                                                     const unsigned short* __restrict__ Bh,
                                                     unsigned short* __restrict__ Qh,
                                                     unsigned short* __restrict__ Kh,
                                                     unsigned short* __restrict__ Vh) {
    __shared__ __align__(16) unsigned short sA[4096], sB[4096];
    const int tid = threadIdx.x;
    const int lane = tid & 63, w = tid >> 6;
    const int wr = (w >> 1) * 64, wc = (w & 1) * 64;
    const int m0 = blockIdx.y * 128, n0 = blockIdx.x * 128;
    f32x4 acc[4][4] = {};

    for (int k0 = 0; k0 < 1024; k0 += 32) {
        GEMM_STAGE_H(Ah, Bh);
        __syncthreads();
        GEMM_BODY_H();
        __syncthreads();
    }

#pragma unroll
    for (int i = 0; i < 4; ++i) {
        int mbase = m0 + wr + i * 16 + (lane >> 4) * 4;
#pragma unroll
        for (int j = 0; j < 4; ++j) {
            int col = n0 + wc + j * 16 + (lane & 15);
            int seg = col >> 10;
            int wcol = col & 1023;
            int h = wcol >> 6, dd = wcol & 63;
            unsigned short* dst = (seg == 0) ? Qh : (seg == 1 ? Kh : Vh);
#pragma unroll
            for (int r = 0; r < 4; ++r) {
                int row = mbase + r;
                int b = row >> 11, n = row & (N_ - 1);
                dst[((size_t)(b * H_ + h) * N_ + n) * D_ + dd] = f2h(acc[i][j][r]);
            }
        }
    }
}

__global__ __launch_bounds__(256) void out_gemm_mfma(const unsigned short* __restrict__ Ah,
                                                     const unsigned short* __restrict__ Bh,
                                                     const float* __restrict__ bias,
                                                     float* __restrict__ C) {
    __shared__ __align__(16) unsigned short sA[4096], sB[4096];
    const int tid = threadIdx.x;
    const int lane = tid & 63, w = tid >> 6;
    const int wr = (w >> 1) * 64, wc = (w & 1) * 64;
    const int m0 = blockIdx.y * 128, n0 = blockIdx.x * 128;
    f32x4 acc[4][4] = {};

    for (int k0 = 0; k0 < 1024; k0 += 32) {
        GEMM_STAGE_H(Ah, Bh);
        __syncthreads();
        GEMM_BODY_H();
        __syncthreads();
    }

#pragma unroll
    for (int i = 0; i < 4; ++i) {
        int mbase = m0 + wr + i * 16 + (lane >> 4) * 4;
#pragma unroll
        for (int j = 0; j < 4; ++j) {
            int col = n0 + wc + j * 16 + (lane & 15);
            float bv = bias[col];
#pragma unroll
            for (int r = 0; r < 4; ++r)
                C[(size_t)(mbase + r) * DIM_ + col] = acc[i][j][r] + bv;
        }
    }
}

// ---------------------------------------------------------------------------
// RoPE in-place on fp16 Q and K. Q pre-scaled by 0.125*log2(e) so the
// attention softmax runs in exp2 domain. freq via exp2f (1 trans op).
// ---------------------------------------------------------------------------
#define QSCALE 0.180336879963f   // 0.125 * log2(e)
__global__ void rope_kernel(unsigned short* __restrict__ Qh,
                            unsigned short* __restrict__ Kh) {
    const int total = B_ * H_ * N_ * (D_ / 2);
    for (int p = blockIdx.x * blockDim.x + threadIdx.x; p < total;
         p += gridDim.x * blockDim.x) {
        int d2 = p & 31;
        int rest = p >> 5;
        int n = rest & (N_ - 1);
        size_t off = (size_t)rest * D_ + 2 * d2;
        // freq = 10000^(-d2/32) = 2^(-d2 * log2(10000)/32)
        float freq = __builtin_amdgcn_exp2f((float)d2 * -0.4152410118f);
        float ang = (float)n * freq;
        float s, c;
        sincosf(ang, &s, &c);

        unsigned int uq = *(unsigned int*)(Qh + off);
        float q0 = h2f((unsigned short)(uq & 0xffff));
        float q1 = h2f((unsigned short)(uq >> 16));
        *(unsigned int*)(Qh + off) =
            (unsigned int)f2h((q0 * c - q1 * s) * QSCALE) |
            ((unsigned int)f2h((q1 * c + q0 * s) * QSCALE) << 16);

        unsigned int uk = *(unsigned int*)(Kh + off);
        float k0 = h2f((unsigned short)(uk & 0xffff));
        float k1 = h2f((unsigned short)(uk >> 16));
        *(unsigned int*)(Kh + off) = (unsigned int)f2h(k0 * c - k1 * s) |
                                     ((unsigned int)f2h(k1 * c + k0 * s) << 16);
    }
}

// ---------------------------------------------------------------------------
// Flash attention (fp16, fp32 softmax/accum): K LDS dbuf XOR-swz; V^T LDS
// dbuf; in-register P; T13 defer-max (THR=8, exp2 domain); cvt_pkrtz P-pack.
// ---------------------------------------------------------------------------
#define PADV 68
#define NT   (N_ / 64)
#define RESC_THR 8.0f
__global__ __launch_bounds__(512, 4) void attn_mfma(const unsigned short* __restrict__ Qh,
                                                    const unsigned short* __restrict__ Kh,
                                                    const unsigned short* __restrict__ Vh,
                                                    unsigned short* __restrict__ Oh) {
    __shared__ __align__(16) unsigned short Ks[2 * 64 * 64];    // K rows, XOR-swz cols
    __shared__ __align__(16) unsigned short Vt[2][64][PADV];    // V^T: [d][kv]
    const int tid = threadIdx.x;
    const int w = tid >> 6;
    const int l = tid & 63;
    const int lr = l & 15, lg = l >> 4;

    // XCD remap: xcd x owns bh in [4x, 4x+4)
    const int f = blockIdx.y * gridDim.x + blockIdx.x;          // 0..511
    const int x = f & 7, g = f >> 3;
    const int bh = x * 4 + (g >> 4);
    const int q0 = (g & 15) * 128;
    const size_t base = (size_t)bh * N_ * D_;

    // K staging coords (pre-swizzled global source, linear LDS dest)
    const int srow = tid >> 3;
    const int scg  = tid & 7;
    const int gcg  = scg ^ (srow & 7);
    const unsigned short* ksrc = Kh + base + (size_t)srow * D_ + gcg * 8;
    unsigned short* kdst = Ks + w * 512;

    // V staging coords
    const int sd0 = (tid & 15) * 4;
    const int skv = (tid >> 4) * 2;

    // Q as B-operand: lane holds col q=lr, k d=lg*8+j (+32h)
    const unsigned short* qrow = Qh + base + (size_t)(q0 + w * 16 + lr) * D_ + lg * 8;
    const half8 qf0 = s2h(*(const short8*)qrow);
    const half8 qf1 = s2h(*(const short8*)(qrow + 32));

    f32x4 oacc[4] = {};                 // [dt]: q=lg*4+r, d=dt*16+lr
    float mrow = -1e30f, lsum = 0.f;

    // ---- prologue: stage tile 0 ----
    gload16(ksrc, kdst);
    {
        short4v r0 = *(const short4v*)(Vh + base + (size_t)(skv + 0) * D_ + sd0);
        short4v r1 = *(const short4v*)(Vh + base + (size_t)(skv + 1) * D_ + sd0);
#pragma unroll
        for (int j = 0; j < 4; ++j) {
            unsigned int pk = (unsigned int)(unsigned short)r0[j] |
                              ((unsigned int)(unsigned short)r1[j] << 16);
            *(unsigned int*)&Vt[0][sd0 + j][skv] = pk;
        }
    }

    for (int ti = 0; ti < NT; ++ti) {
        const int cur = ti & 1, nxt = cur ^ 1;
        __syncthreads();

        // ---- issue tile ti+1 staging early ----
        short4v n0v = {}, n1v = {};
        if (ti + 1 < NT) {
            gload16(ksrc + (size_t)(ti + 1) * 64 * D_, kdst + nxt * 4096);
            const unsigned short* nsrc = Vh + base + (size_t)((ti + 1) * 64 + skv) * D_ + sd0;
            n0v = *(const short4v*)nsrc;
            n1v = *(const short4v*)(nsrc + D_);
        }

        // ---- QK(ti): S^T = K.Q^T, K A-frags from swizzled LDS ----
        f32x4 sacc[4] = {};
        __builtin_amdgcn_s_setprio(1);
#pragma unroll
        for (int t = 0; t < 4; ++t) {
            int row = t * 16 + lr;
            int swz = (row & 7);
            const unsigned short* kr = Ks + cur * 4096 + row * 64;
            half8 kf0 = s2h(*(const short8*)(kr + (lg ^ swz) * 8));
            half8 kf1 = s2h(*(const short8*)(kr + ((lg + 4) ^ swz) * 8));
            sacc[t] = __builtin_amdgcn_mfma_f32_16x16x32_f16(kf0, qf0, sacc[t], 0, 0, 0);
            sacc[t] = __builtin_amdgcn_mfma_f32_16x16x32_f16(kf1, qf1, sacc[t], 0, 0, 0);
        }
        __builtin_amdgcn_s_setprio(0);

        // ---- softmax (exp2 domain), T13 defer-max ----
        float tm0 = fmaxf(fmaxf(sacc[0][0], sacc[0][1]), fmaxf(sacc[0][2], sacc[0][3]));
        float tm1 = fmaxf(fmaxf(sacc[1][0], sacc[1][1]), fmaxf(sacc[1][2], sacc[1][3]));
        float tm2 = fmaxf(fmaxf(sacc[2][0], sacc[2][1]), fmaxf(sacc[2][2], sacc[2][3]));
        float tm3 = fmaxf(fmaxf(sacc[3][0], sacc[3][1]), fmaxf(sacc[3][2], sacc[3][3]));
        float tm = fmaxf(fmaxf(tm0, tm1), fmaxf(tm2, tm3));
        tm = fmaxf(tm, __shfl_xor(tm, 16));
        tm = fmaxf(tm, __shfl_xor(tm, 32));

        if (!__all(tm - mrow <= RESC_THR)) {
            float nm = fmaxf(mrow, tm);
            float al = __builtin_amdgcn_exp2f(mrow - nm);
            mrow = nm;
            lsum *= al;
#pragma unroll
            for (int r = 0; r < 4; ++r) {
                float alq = __shfl(al, lg * 4 + r);
#pragma unroll
                for (int dt = 0; dt < 4; ++dt) oacc[dt][r] *= alq;
            }
        }

        h8u pu[2];
        float ps = 0.f;
#pragma unroll
        for (int t = 0; t < 4; ++t) {
            float e0 = __builtin_amdgcn_exp2f(sacc[t][0] - mrow);
            float e1 = __builtin_amdgcn_exp2f(sacc[t][1] - mrow);
            float e2 = __builtin_amdgcn_exp2f(sacc[t][2] - mrow);
            float e3 = __builtin_amdgcn_exp2f(sacc[t][3] - mrow);
            ps += (e0 + e1) + (e2 + e3);
            pu[t >> 1].h2[(t & 1) * 2]     = __builtin_amdgcn_cvt_pkrtz(e0, e1);
            pu[t >> 1].h2[(t & 1) * 2 + 1] = __builtin_amdgcn_cvt_pkrtz(e2, e3);
        }
        ps += __shfl_xor(ps, 16);
        ps += __shfl_xor(ps, 32);
        lsum += ps;

        // ---- PV(ti) ----
        __builtin_amdgcn_s_setprio(1);
#pragma unroll
        for (int m2 = 0; m2 < 2; ++m2)
#pragma unroll
            for (int dt = 0; dt < 4; ++dt) {
                short4v v0 = *(const short4v*)&Vt[cur][dt * 16 + lr][m2 * 32 + lg * 4];
                short4v v1 = *(const short4v*)&Vt[cur][dt * 16 + lr][m2 * 32 + 16 + lg * 4];
                short8 vb = {v0[0], v0[1], v0[2], v0[3], v1[0], v1[1], v1[2], v1[3]};
                oacc[dt] = __builtin_amdgcn_mfma_f32_16x16x32_f16(pu[m2].h, s2h(vb), oacc[dt], 0, 0, 0);
            }
        __builtin_amdgcn_s_setprio(0);

        // ---- commit V(ti+1) ----
        if (ti + 1 < NT) {
#pragma unroll
            for (int j = 0; j < 4; ++j) {
                unsigned int pk = (unsigned int)(unsigned short)n0v[j] |
                                  ((unsigned int)(unsigned short)n1v[j] << 16);
                *(unsigned int*)&Vt[nxt][sd0 + j][skv] = pk;
            }
        }
    }

    // ---- epilogue ----
    int b = bh >> 4, h = bh & 15;
#pragma unroll
    for (int r = 0; r < 4; ++r) {
        float ls = __shfl(lsum, lg * 4 + r);
        float inv = 1.0f / ls;
        size_t orow = ((size_t)b * N_ + q0 + w * 16 + lg * 4 + r) * INNER_ + h * 64 + lr;
#pragma unroll
        for (int dt = 0; dt < 4; ++dt)
            Oh[orow + 16 * dt] = f2h(oacc[dt][r] * inv);
    }
}

// ---------------------------------------------------------------------------
extern "C" void kernel_launch(void* const* d_in, const int* in_sizes, int n_in,
                              void* d_out, int out_size, void* d_ws, size_t ws_size,
                              hipStream_t stream) {
    const float* x     = (const float*)d_in[0];
    const float* w_qkv = (const float*)d_in[1];
    const float* w_out = (const float*)d_in[2];
    const float* b_out = (const float*)d_in[3];
    float* out = (float*)d_out;

    unsigned short* Xh  = (unsigned short*)d_ws;     // 4M elems (reused as Oh)
    unsigned short* WqT = Xh + 4194304;              // 3M
    unsigned short* WoT = WqT + 3145728;             // 1M
    unsigned short* Qh  = WoT + 1048576;             // 4M
    unsigned short* Kh  = Qh + 4194304;              // 4M
    unsigned short* Vh  = Kh + 4194304;              // 4M

    convert_x<<<dim3(2048), 256, 0, stream>>>(x, Xh);
    convert_w_T<<<dim3(QKVC_ / 64, 16), 256, 0, stream>>>(w_qkv, WqT, QKVC_);
    convert_w_T<<<dim3(DIM_ / 64, 16), 256, 0, stream>>>(w_out, WoT, DIM_);

    qkv_gemm_mfma<<<dim3(QKVC_ / 128, 32), 256, 0, stream>>>(Xh, WqT, Qh, Kh, Vh);
    rope_kernel<<<dim3(2048), 256, 0, stream>>>(Qh, Kh);
    attn_mfma<<<dim3(N_ / 128, B_ * H_), 512, 0, stream>>>(Qh, Kh, Vh, Xh);
    out_gemm_mfma<<<dim3(DIM_ / 128, 32), 256, 0, stream>>>(Xh, WoT, b_out, out);
}